// Round 6
// baseline (400.205 us; speedup 1.0000x reference)
//
#include <hip/hip_runtime.h>
#include <hip/hip_bf16.h>

// ---------------- types & helpers ----------------
typedef float f32x4 __attribute__((ext_vector_type(4)));
typedef short bf16x8 __attribute__((ext_vector_type(8)));

#define M_NT 16     // meta[16]     number of m-tiles
#define M_OFF 17    // meta[17..24] 256-aligned segment offsets
#define M_TBL 32    // meta[32..]   tile table: int4 {expert, base, valid, 0}
#define MAX_TILES 136   // 256-row tiles: <= 128 + 7
#define NCHUNK 1024     // router blocks; 16 tokens per chunk

__device__ __forceinline__ void gload16(const void* g, void* l) {
  __builtin_amdgcn_global_load_lds(
      (const __attribute__((address_space(1))) void*)g,
      (__attribute__((address_space(3))) void*)l, 16, 0, 0);
}

__device__ __forceinline__ float bf2f(unsigned short u) {
  union { unsigned int i; float f; } v; v.i = ((unsigned int)u) << 16; return v.f;
}
__device__ __forceinline__ unsigned short f2bf(float f) {
  __hip_bfloat16 h = __float2bfloat16(f);
  return __builtin_bit_cast(unsigned short, h);
}

// compiler memory fence + hw barrier, NO sched_barrier (m141: order-pinning regresses)
#define CBAR() do { asm volatile("" ::: "memory"); __builtin_amdgcn_s_barrier(); asm volatile("" ::: "memory"); } while (0)

// src fp32 [B][R][C] -> dst bf16 [B][C][R]
__global__ void transpose_cvt(const float* __restrict__ src,
                              unsigned short* __restrict__ dst, int R, int C) {
  __shared__ float tile[32][33];
  int b = blockIdx.z;
  int c0 = blockIdx.x * 32, r0 = blockIdx.y * 32;
  src += (size_t)b * R * C;
  dst += (size_t)b * R * C;
  int tx = threadIdx.x, ty = threadIdx.y;  // 32 x 8
#pragma unroll
  for (int i = 0; i < 32; i += 8)
    tile[ty + i][tx] = src[(size_t)(r0 + ty + i) * C + c0 + tx];
  __syncthreads();
#pragma unroll
  for (int i = 0; i < 32; i += 8)
    dst[(size_t)(c0 + ty + i) * R + r0 + tx] = f2bf(tile[tx][ty + i]);
}

// ---------------- router: fp32 logits, softmax, top-2, fused x->bf16 ----------------
__global__ __launch_bounds__(256) void router_kernel(
    const float* __restrict__ x, const float* __restrict__ Wr,
    const float* __restrict__ br, unsigned short* __restrict__ xbf,
    float* __restrict__ scores, int* __restrict__ idx,
    int* __restrict__ blk_hist) {
  __shared__ int cnt[8];
  int tid = threadIdx.x, lane = tid & 63, w = tid >> 6;
  if (tid < 8) cnt[tid] = 0;
  __syncthreads();
  int t0 = blockIdx.x * 16 + w * 4;
  const float* xr = x + (size_t)t0 * 2048;
  unsigned short* xo = xbf + (size_t)t0 * 2048;
  float acc[4][8] = {};
#pragma unroll
  for (int j = 0; j < 8; ++j) {
    int h0 = j * 256 + lane * 4;
    float4 xv[4];
#pragma unroll
    for (int t = 0; t < 4; ++t) xv[t] = *(const float4*)(xr + (size_t)t * 2048 + h0);
#pragma unroll
    for (int t = 0; t < 4; ++t) {
      ushort4 p;
      p.x = f2bf(xv[t].x); p.y = f2bf(xv[t].y);
      p.z = f2bf(xv[t].z); p.w = f2bf(xv[t].w);
      *(ushort4*)(xo + (size_t)t * 2048 + h0) = p;
    }
    const float4* wp = (const float4*)(Wr + (size_t)h0 * 8);
#pragma unroll
    for (int c = 0; c < 4; ++c) {
      float4 w0 = wp[2 * c], w1 = wp[2 * c + 1];
      float xc0 = (c == 0) ? xv[0].x : (c == 1) ? xv[0].y : (c == 2) ? xv[0].z : xv[0].w;
      float xc1 = (c == 0) ? xv[1].x : (c == 1) ? xv[1].y : (c == 2) ? xv[1].z : xv[1].w;
      float xc2 = (c == 0) ? xv[2].x : (c == 1) ? xv[2].y : (c == 2) ? xv[2].z : xv[2].w;
      float xc3 = (c == 0) ? xv[3].x : (c == 1) ? xv[3].y : (c == 2) ? xv[3].z : xv[3].w;
      acc[0][0] += xc0 * w0.x; acc[0][1] += xc0 * w0.y; acc[0][2] += xc0 * w0.z; acc[0][3] += xc0 * w0.w;
      acc[0][4] += xc0 * w1.x; acc[0][5] += xc0 * w1.y; acc[0][6] += xc0 * w1.z; acc[0][7] += xc0 * w1.w;
      acc[1][0] += xc1 * w0.x; acc[1][1] += xc1 * w0.y; acc[1][2] += xc1 * w0.z; acc[1][3] += xc1 * w0.w;
      acc[1][4] += xc1 * w1.x; acc[1][5] += xc1 * w1.y; acc[1][6] += xc1 * w1.z; acc[1][7] += xc1 * w1.w;
      acc[2][0] += xc2 * w0.x; acc[2][1] += xc2 * w0.y; acc[2][2] += xc2 * w0.z; acc[2][3] += xc2 * w0.w;
      acc[2][4] += xc2 * w1.x; acc[2][5] += xc2 * w1.y; acc[2][6] += xc2 * w1.z; acc[2][7] += xc2 * w1.w;
      acc[3][0] += xc3 * w0.x; acc[3][1] += xc3 * w0.y; acc[3][2] += xc3 * w0.z; acc[3][3] += xc3 * w0.w;
      acc[3][4] += xc3 * w1.x; acc[3][5] += xc3 * w1.y; acc[3][6] += xc3 * w1.z; acc[3][7] += xc3 * w1.w;
    }
  }
#pragma unroll
  for (int t = 0; t < 4; ++t)
#pragma unroll
    for (int e = 0; e < 8; ++e)
#pragma unroll
      for (int off = 32; off > 0; off >>= 1)
        acc[t][e] += __shfl_xor(acc[t][e], off);
  if (lane < 4) {
    int t = t0 + lane;
    float l[8];
#pragma unroll
    for (int e = 0; e < 8; ++e) {
      float v = (lane == 0) ? acc[0][e] : (lane == 1) ? acc[1][e]
              : (lane == 2) ? acc[2][e] : acc[3][e];
      l[e] = v + br[e];
    }
    float mx = l[0];
#pragma unroll
    for (int e = 1; e < 8; ++e) mx = fmaxf(mx, l[e]);
    float se = 0.f;
#pragma unroll
    for (int e = 0; e < 8; ++e) se += __expf(l[e] - mx);
    float inv = 1.f / se;
    int e1 = 0; float b1 = l[0];
#pragma unroll
    for (int e = 1; e < 8; ++e) if (l[e] > b1) { b1 = l[e]; e1 = e; }
    int e2 = -1; float b2 = -1e30f;
#pragma unroll
    for (int e = 0; e < 8; ++e) if (e != e1 && l[e] > b2) { b2 = l[e]; e2 = e; }
    idx[2 * t] = e1; idx[2 * t + 1] = e2;
    scores[2 * t] = __expf(b1 - mx) * inv;
    scores[2 * t + 1] = __expf(b2 - mx) * inv;
    atomicAdd(&cnt[e1], 1);   // LDS atomics only
    atomicAdd(&cnt[e2], 1);
  }
  __syncthreads();
  if (tid < 8) blk_hist[blockIdx.x * 8 + tid] = cnt[tid];
}

// ---------------- scan: parallel prefix over chunk histograms (256-row tiles) ----------------
__global__ __launch_bounds__(512) void scan_kernel(
    const int* __restrict__ blk_hist, int* __restrict__ chunk_base,
    int* __restrict__ meta, int* __restrict__ rowlist) {
  __shared__ int stot[8], soff[8];
  int tid = threadIdx.x, lane = tid & 63, e = tid >> 6;
  int running = 0;
  for (int g = 0; g < NCHUNK / 64; ++g) {
    int c = g * 64 + lane;
    int v = blk_hist[c * 8 + e];
    int orig = v;
#pragma unroll
    for (int off = 1; off < 64; off <<= 1) {
      int n = __shfl_up(v, off);
      if (lane >= off) v += n;
    }
    chunk_base[c * 8 + e] = running + v - orig;
    running += __shfl(v, 63);
  }
  if (lane == 0) stot[e] = running;
  __syncthreads();
  if (tid == 0) {
    int off = 0, nt = 0;
    int4* tbl = (int4*)(meta + M_TBL);
    for (int ee = 0; ee < 8; ++ee) {
      int c = stot[ee];
      meta[M_OFF + ee] = off; soff[ee] = off;
      int tiles = (c + 255) >> 8;
      for (int t = 0; t < tiles; ++t)
        tbl[nt++] = make_int4(ee, off + t * 256, min(256, c - t * 256), 0);
      off += tiles << 8;
    }
    meta[M_NT] = nt;
  }
  __syncthreads();
  for (int ee = 0; ee < 8; ++ee) {
    int c = stot[ee], end = ((c + 255) >> 8) << 8;
    for (int i = c + tid; i < end; i += 512) rowlist[soff[ee] + i] = 0;
  }
}

// ---------------- scatter: ballot-ranked, zero atomics ----------------
__global__ void scatter_kernel(const int* __restrict__ idx,
                               const int* __restrict__ chunk_base,
                               const int* __restrict__ meta,
                               int* __restrict__ rowlist) {
  int c = blockIdx.x, lane = threadIdx.x;
  int entry = c * 32 + lane;
  int e = (lane < 32) ? idx[entry] : -1;
#pragma unroll
  for (int ee = 0; ee < 8; ++ee) {
    unsigned long long m = __ballot(e == ee);
    if (e == ee) {
      int rank = __popcll(m & ((1ull << lane) - 1));
      rowlist[meta[M_OFF + ee] + chunk_base[c * 8 + ee] + rank] = entry;
    }
  }
}

// ============ 256x256 8-phase GEMM ============
// 512 thr = 8 waves (2M x 4N); BK=64. LDS 128KiB: B at 0, A at 65536;
// each: 2 dbuf x 2 half x (128 rows x 64 k) bf16.
// Stage placement (race-audited: each issues after the barrier ending its
// region's last read): ph0: A1(t+1); ph2: B0(t+2), B1(t+2); ph3: A0(t+2).
// vmcnt(6) once per K-tile (retires exactly through A1(t+1)); vmcnt(0) drain at tail.
// NO sched_barrier, NO manual lgkmcnt: compiler emits counted lgkmcnt for
// visible ds_read->MFMA deps (m97/m141 evidence).

// ---------------- expert GEMM: z[entry] = (x[t] @ We[e] + be[e]) * score ----------------
__global__ __launch_bounds__(512, 2) void expert_gemm(
    const unsigned short* __restrict__ xbf,   // [16384][2048] bf16
    const unsigned short* __restrict__ WeT,   // [8][1024][2048] bf16 (n-major)
    const float* __restrict__ be,             // [8][1024]
    const float* __restrict__ scores,         // [32768]
    const int* __restrict__ rowlist,
    const int* __restrict__ meta,
    unsigned short* __restrict__ z) {         // [32768][1024] bf16
  __shared__ char smem[131072];
  __shared__ int lrows[256];
  int nt = meta[M_NT];
  int flat = blockIdx.y * 4 + blockIdx.x;       // 544 blocks
  int work = (flat & 7) * 68 + (flat >> 3);     // XCD-contiguous chunks of 68
  int tileid = work >> 2, nb = work & 3;
  if (tileid >= nt) return;
  int4 tt = ((const int4*)(meta + M_TBL))[tileid];
  int e = tt.x, base = tt.y, valid = tt.z;
  int n0 = nb * 256;
  int tid = threadIdx.x, lane = tid & 63, w = tid >> 6;
  if (tid < 256) lrows[tid] = rowlist[base + tid];
  __syncthreads();
  int wm = w >> 2, wn = w & 3;
  int fl = lane & 15, q = lane >> 4;
  // staging geometry
  int rowb = tid >> 3;                 // 0..63
  int dstB = rowb * 128 + (tid & 7) * 16;   // linear LDS dest
  int s16 = ((tid & 7) ^ (rowb & 7)) * 16;  // inverse-swizzled source slot
  const char* pa[2][2]; const char* pb[2][2];
#pragma unroll
  for (int h = 0; h < 2; ++h)
#pragma unroll
    for (int j = 0; j < 2; ++j) {
      int R = h * 128 + j * 64 + rowb;
      pa[h][j] = (const char*)xbf + (size_t)(lrows[R] >> 1) * 4096 + s16;
      pb[h][j] = (const char*)WeT + ((size_t)e * 1024 + n0 + R) * 4096 + s16;
    }
#define ESTAGE(OP, H, TS) { \
    char* d_ = smem + (OP) * 65536 + ((TS) & 1) * 32768 + (H) * 16384 + dstB; \
    gload16(((OP) ? pa[H][0] : pb[H][0]) + (size_t)(TS) * 128, d_); \
    gload16(((OP) ? pa[H][1] : pb[H][1]) + (size_t)(TS) * 128, d_ + 8192); }
  // read address pieces
  int sw16 = (fl & 7) << 4;
  int axk0 = (q * 16) ^ sw16, axk1 = (64 + q * 16) ^ sw16;
  int Arow = wm * 128 + fl;   // + half*64 + m*16
  int Brow = wn * 64 + fl;    // + nh*32 + n*16
  // prologue: stage half-slots 0..6 (K-tile 0 full + B0,B1,A0 of K-tile 1)
  ESTAGE(0, 0, 0); ESTAGE(0, 1, 0); ESTAGE(1, 0, 0); ESTAGE(1, 1, 0);
  ESTAGE(0, 0, 1); ESTAGE(0, 1, 1); ESTAGE(1, 0, 1);
  asm volatile("s_waitcnt vmcnt(6)" ::: "memory");
  CBAR();
  f32x4 acc[8][4] = {};
  bf16x8 av[4][2], bv0[2][2], bv1[2][2];
  const int NT = 32;  // K=2048/64
  for (int t = 0; t < NT; ++t) {
    int dby = (t & 1) * 32768;
    // ---- phase 0: quad(0,0) ----
#pragma unroll
    for (int m = 0; m < 4; ++m) {
      const char* p_ = smem + 65536 + dby + (Arow + m * 16) * 128;
      av[m][0] = *(const bf16x8*)(p_ + axk0);
      av[m][1] = *(const bf16x8*)(p_ + axk1);
    }
#pragma unroll
    for (int n = 0; n < 2; ++n) {
      const char* p_ = smem + dby + (Brow + n * 16) * 128;
      bv0[n][0] = *(const bf16x8*)(p_ + axk0);
      bv0[n][1] = *(const bf16x8*)(p_ + axk1);
    }
    if (t + 1 < NT) ESTAGE(1, 1, t + 1);     // A1 of t+1 (other buffer)
    CBAR();
    __builtin_amdgcn_s_setprio(1);
#pragma unroll
    for (int kk = 0; kk < 2; ++kk)
#pragma unroll
      for (int m = 0; m < 4; ++m)
#pragma unroll
        for (int n = 0; n < 2; ++n)
          acc[m][n] = __builtin_amdgcn_mfma_f32_16x16x32_bf16(av[m][kk], bv0[n][kk], acc[m][n], 0, 0, 0);
    __builtin_amdgcn_s_setprio(0);
    CBAR();
    // ---- phase 1: quad(0,1) ----
#pragma unroll
    for (int n = 0; n < 2; ++n) {
      const char* p_ = smem + dby + (Brow + 32 + n * 16) * 128;
      bv1[n][0] = *(const bf16x8*)(p_ + axk0);
      bv1[n][1] = *(const bf16x8*)(p_ + axk1);
    }
    CBAR();
    __builtin_amdgcn_s_setprio(1);
#pragma unroll
    for (int kk = 0; kk < 2; ++kk)
#pragma unroll
      for (int m = 0; m < 4; ++m)
#pragma unroll
        for (int n = 0; n < 2; ++n)
          acc[m][2 + n] = __builtin_amdgcn_mfma_f32_16x16x32_bf16(av[m][kk], bv1[n][kk], acc[m][2 + n], 0, 0, 0);
    __builtin_amdgcn_s_setprio(0);
    CBAR();
    // ---- phase 2: quad(1,0) ---- (B regions free after ph1 -> stage B of t+2)
#pragma unroll
    for (int m = 0; m < 4; ++m) {
      const char* p_ = smem + 65536 + dby + (Arow + 64 + m * 16) * 128;
      av[m][0] = *(const bf16x8*)(p_ + axk0);
      av[m][1] = *(const bf16x8*)(p_ + axk1);
    }
    if (t + 2 < NT) { ESTAGE(0, 0, t + 2); ESTAGE(0, 1, t + 2); }
    CBAR();
    __builtin_amdgcn_s_setprio(1);
#pragma unroll
    for (int kk = 0; kk < 2; ++kk)
#pragma unroll
      for (int m = 0; m < 4; ++m)
#pragma unroll
        for (int n = 0; n < 2; ++n)
          acc[4 + m][n] = __builtin_amdgcn_mfma_f32_16x16x32_bf16(av[m][kk], bv0[n][kk], acc[4 + m][n], 0, 0, 0);
    __builtin_amdgcn_s_setprio(0);
    CBAR();
    // ---- phase 3: quad(1,1) ---- (A0 region free after ph2 -> stage A0 of t+2)
    if (t + 2 < NT) ESTAGE(1, 0, t + 2);
    CBAR();
    __builtin_amdgcn_s_setprio(1);
#pragma unroll
    for (int kk = 0; kk < 2; ++kk)
#pragma unroll
      for (int m = 0; m < 4; ++m)
#pragma unroll
        for (int n = 0; n < 2; ++n)
          acc[4 + m][2 + n] = __builtin_amdgcn_mfma_f32_16x16x32_bf16(av[m][kk], bv1[n][kk], acc[4 + m][2 + n], 0, 0, 0);
    __builtin_amdgcn_s_setprio(0);
    if (t < NT - 2) { asm volatile("s_waitcnt vmcnt(6)" ::: "memory"); }
    else            { asm volatile("s_waitcnt vmcnt(0)" ::: "memory"); }
    CBAR();
  }
#undef ESTAGE
  // epilogue
  float bev[4];
#pragma unroll
  for (int nc = 0; nc < 4; ++nc)
    bev[nc] = be[e * 1024 + n0 + wn * 64 + (nc >> 1) * 32 + (nc & 1) * 16 + fl];
#pragma unroll
  for (int mi = 0; mi < 8; ++mi) {
    int rowbase = wm * 128 + (mi >> 2) * 64 + (mi & 3) * 16 + q * 4;
#pragma unroll
    for (int r = 0; r < 4; ++r) {
      int row = rowbase + r;
      if (row < valid) {
        int entry = lrows[row];
        float s = scores[entry];
        unsigned short* zr = z + (size_t)entry * 1024 + n0 + wn * 64 + fl;
#pragma unroll
        for (int nc = 0; nc < 4; ++nc)
          zr[(nc >> 1) * 32 + (nc & 1) * 16] = f2bf((acc[mi][nc][r] + bev[nc]) * s);
      }
    }
  }
}

// ---------------- combine GEMM: out = y @ Wc + bc (fp32 out) ----------------
__global__ __launch_bounds__(512, 2) void combine_gemm(
    const unsigned short* __restrict__ y,    // [16384][1024] bf16
    const unsigned short* __restrict__ WcT,  // [2048][1024] bf16 (n-major)
    const float* __restrict__ bc,            // [2048]
    float* __restrict__ out) {               // [16384][2048] fp32
  __shared__ char smem[131072];
  int flat = blockIdx.y * 8 + blockIdx.x;     // 512 blocks
  int work = (flat & 7) * 64 + (flat >> 3);
  int mtile = work >> 3, nb = work & 7;
  int m0 = mtile * 256, n0 = nb * 256;
  int tid = threadIdx.x, lane = tid & 63, w = tid >> 6;
  int wm = w >> 2, wn = w & 3;
  int fl = lane & 15, q = lane >> 4;
  int rowb = tid >> 3;
  int dstB = rowb * 128 + (tid & 7) * 16;
  int s16 = ((tid & 7) ^ (rowb & 7)) * 16;
  const char* pa[2][2]; const char* pb[2][2];
#pragma unroll
  for (int h = 0; h < 2; ++h)
#pragma unroll
    for (int j = 0; j < 2; ++j) {
      int R = h * 128 + j * 64 + rowb;
      pa[h][j] = (const char*)y + (size_t)(m0 + R) * 2048 + s16;
      pb[h][j] = (const char*)WcT + (size_t)(n0 + R) * 2048 + s16;
    }
#define CSTAGE(OP, H, TS) { \
    char* d_ = smem + (OP) * 65536 + ((TS) & 1) * 32768 + (H) * 16384 + dstB; \
    gload16(((OP) ? pa[H][0] : pb[H][0]) + (size_t)(TS) * 128, d_); \
    gload16(((OP) ? pa[H][1] : pb[H][1]) + (size_t)(TS) * 128, d_ + 8192); }
  int sw16 = (fl & 7) << 4;
  int axk0 = (q * 16) ^ sw16, axk1 = (64 + q * 16) ^ sw16;
  int Arow = wm * 128 + fl;
  int Brow = wn * 64 + fl;
  CSTAGE(0, 0, 0); CSTAGE(0, 1, 0); CSTAGE(1, 0, 0); CSTAGE(1, 1, 0);
  CSTAGE(0, 0, 1); CSTAGE(0, 1, 1); CSTAGE(1, 0, 1);
  asm volatile("s_waitcnt vmcnt(6)" ::: "memory");
  CBAR();
  f32x4 acc[8][4] = {};
  bf16x8 av[4][2], bv0[2][2], bv1[2][2];
  const int NT = 16;  // K=1024/64
  for (int t = 0; t < NT; ++t) {
    int dby = (t & 1) * 32768;
    // ---- phase 0 ----
#pragma unroll
    for (int m = 0; m < 4; ++m) {
      const char* p_ = smem + 65536 + dby + (Arow + m * 16) * 128;
      av[m][0] = *(const bf16x8*)(p_ + axk0);
      av[m][1] = *(const bf16x8*)(p_ + axk1);
    }
#pragma unroll
    for (int n = 0; n < 2; ++n) {
      const char* p_ = smem + dby + (Brow + n * 16) * 128;
      bv0[n][0] = *(const bf16x8*)(p_ + axk0);
      bv0[n][1] = *(const bf16x8*)(p_ + axk1);
    }
    if (t + 1 < NT) CSTAGE(1, 1, t + 1);
    CBAR();
    __builtin_amdgcn_s_setprio(1);
#pragma unroll
    for (int kk = 0; kk < 2; ++kk)
#pragma unroll
      for (int m = 0; m < 4; ++m)
#pragma unroll
        for (int n = 0; n < 2; ++n)
          acc[m][n] = __builtin_amdgcn_mfma_f32_16x16x32_bf16(av[m][kk], bv0[n][kk], acc[m][n], 0, 0, 0);
    __builtin_amdgcn_s_setprio(0);
    CBAR();
    // ---- phase 1 ----
#pragma unroll
    for (int n = 0; n < 2; ++n) {
      const char* p_ = smem + dby + (Brow + 32 + n * 16) * 128;
      bv1[n][0] = *(const bf16x8*)(p_ + axk0);
      bv1[n][1] = *(const bf16x8*)(p_ + axk1);
    }
    CBAR();
    __builtin_amdgcn_s_setprio(1);
#pragma unroll
    for (int kk = 0; kk < 2; ++kk)
#pragma unroll
      for (int m = 0; m < 4; ++m)
#pragma unroll
        for (int n = 0; n < 2; ++n)
          acc[m][2 + n] = __builtin_amdgcn_mfma_f32_16x16x32_bf16(av[m][kk], bv1[n][kk], acc[m][2 + n], 0, 0, 0);
    __builtin_amdgcn_s_setprio(0);
    CBAR();
    // ---- phase 2 ----
#pragma unroll
    for (int m = 0; m < 4; ++m) {
      const char* p_ = smem + 65536 + dby + (Arow + 64 + m * 16) * 128;
      av[m][0] = *(const bf16x8*)(p_ + axk0);
      av[m][1] = *(const bf16x8*)(p_ + axk1);
    }
    if (t + 2 < NT) { CSTAGE(0, 0, t + 2); CSTAGE(0, 1, t + 2); }
    CBAR();
    __builtin_amdgcn_s_setprio(1);
#pragma unroll
    for (int kk = 0; kk < 2; ++kk)
#pragma unroll
      for (int m = 0; m < 4; ++m)
#pragma unroll
        for (int n = 0; n < 2; ++n)
          acc[4 + m][n] = __builtin_amdgcn_mfma_f32_16x16x32_bf16(av[m][kk], bv0[n][kk], acc[4 + m][n], 0, 0, 0);
    __builtin_amdgcn_s_setprio(0);
    CBAR();
    // ---- phase 3 ----
    if (t + 2 < NT) CSTAGE(1, 0, t + 2);
    CBAR();
    __builtin_amdgcn_s_setprio(1);
#pragma unroll
    for (int kk = 0; kk < 2; ++kk)
#pragma unroll
      for (int m = 0; m < 4; ++m)
#pragma unroll
        for (int n = 0; n < 2; ++n)
          acc[4 + m][2 + n] = __builtin_amdgcn_mfma_f32_16x16x32_bf16(av[m][kk], bv1[n][kk], acc[4 + m][2 + n], 0, 0, 0);
    __builtin_amdgcn_s_setprio(0);
    if (t < NT - 2) { asm volatile("s_waitcnt vmcnt(6)" ::: "memory"); }
    else            { asm volatile("s_waitcnt vmcnt(0)" ::: "memory"); }
    CBAR();
  }
#undef CSTAGE
  float bcv[4];
#pragma unroll
  for (int nc = 0; nc < 4; ++nc)
    bcv[nc] = bc[n0 + wn * 64 + (nc >> 1) * 32 + (nc & 1) * 16 + fl];
#pragma unroll
  for (int mi = 0; mi < 8; ++mi) {
    int rowbase = m0 + wm * 128 + (mi >> 2) * 64 + (mi & 3) * 16 + q * 4;
#pragma unroll
    for (int r = 0; r < 4; ++r) {
      float* orow = out + (size_t)(rowbase + r) * 2048 + n0 + wn * 64 + fl;
#pragma unroll
      for (int nc = 0; nc < 4; ++nc)
        orow[(nc >> 1) * 32 + (nc & 1) * 16] = acc[mi][nc][r] + bcv[nc];
    }
  }
}

// ---------------- weighted sum: y[t] = z[2t] + z[2t+1] (both pre-weighted) ----------------
__global__ void wsum_kernel(const unsigned short* __restrict__ z,
                            unsigned short* __restrict__ y) {
  size_t i = ((size_t)blockIdx.x * 256 + threadIdx.x) * 8;
  size_t t = i >> 10, d = i & 1023;
  int4 za = *(const int4*)(z + (t * 2) * 1024 + d);
  int4 zb = *(const int4*)(z + (t * 2 + 1) * 1024 + d);
  int4 r;
  const unsigned short* pa = (const unsigned short*)&za;
  const unsigned short* pb = (const unsigned short*)&zb;
  unsigned short* pr = (unsigned short*)&r;
#pragma unroll
  for (int j = 0; j < 8; ++j) pr[j] = f2bf(bf2f(pa[j]) + bf2f(pb[j]));
  *(int4*)(y + i) = r;
}

// ---------------- launch ----------------
extern "C" void kernel_launch(void* const* d_in, const int* in_sizes, int n_in,
                              void* d_out, int out_size, void* d_ws, size_t ws_size,
                              hipStream_t stream) {
  const float* x  = (const float*)d_in[0];
  const float* Wr = (const float*)d_in[1];
  const float* br = (const float*)d_in[2];
  const float* We = (const float*)d_in[3];
  const float* be = (const float*)d_in[4];
  const float* Wc = (const float*)d_in[5];
  const float* bc = (const float*)d_in[6];
  float* out = (float*)d_out;

  char* ws = (char*)d_ws;
  size_t o = 0;
  auto alloc = [&](size_t b) {
    char* p = ws + o;
    o = (o + b + 255) & ~(size_t)255;
    return p;
  };
  unsigned short* xbf = (unsigned short*)alloc(16384UL * 2048 * 2);
  unsigned short* WeT = (unsigned short*)alloc(8UL * 1024 * 2048 * 2);
  unsigned short* WcT = (unsigned short*)alloc(2048UL * 1024 * 2);
  unsigned short* z   = (unsigned short*)alloc(32768UL * 1024 * 2);
  unsigned short* yw  = (unsigned short*)alloc(16384UL * 1024 * 2);
  float* scores = (float*)alloc(32768UL * 4);
  int* idx      = (int*)alloc(32768UL * 4);
  int* rowlist  = (int*)alloc(36864UL * 4);
  int* meta     = (int*)alloc(8192);
  int* blk_hist = (int*)alloc(NCHUNK * 8 * 4);
  int* chunk_base = (int*)alloc(NCHUNK * 8 * 4);
  (void)ws_size; (void)in_sizes; (void)n_in; (void)out_size;

  hipLaunchKernelGGL(transpose_cvt, dim3(32, 64, 8), dim3(32, 8), 0, stream, We, WeT, 2048, 1024);
  hipLaunchKernelGGL(transpose_cvt, dim3(64, 32, 1), dim3(32, 8), 0, stream, Wc, WcT, 1024, 2048);
  hipLaunchKernelGGL(router_kernel, dim3(NCHUNK), dim3(256), 0, stream, x, Wr, br, xbf, scores, idx, blk_hist);
  hipLaunchKernelGGL(scan_kernel, dim3(1), dim3(512), 0, stream, blk_hist, chunk_base, meta, rowlist);
  hipLaunchKernelGGL(scatter_kernel, dim3(NCHUNK), dim3(64), 0, stream, idx, chunk_base, meta, rowlist);
  hipLaunchKernelGGL(expert_gemm, dim3(4, MAX_TILES), dim3(512), 0, stream,
                     xbf, WeT, be, scores, rowlist, meta, z);
  hipLaunchKernelGGL(wsum_kernel, dim3(8192), dim3(256), 0, stream, z, yw);
  hipLaunchKernelGGL(combine_gemm, dim3(8, 64), dim3(512), 0, stream, yw, WcT, bc, out);
}

// Round 7
// 383.874 us; speedup vs baseline: 1.0425x; 1.0425x over previous
//
#include <hip/hip_runtime.h>
#include <hip/hip_bf16.h>

// ---------------- types & helpers ----------------
typedef float f32x4 __attribute__((ext_vector_type(4)));
typedef short bf16x8 __attribute__((ext_vector_type(8)));

#define M_NT 16     // meta[16]     number of m-tiles
#define M_OFF 17    // meta[17..24] 256-aligned segment offsets
#define M_TBL 32    // meta[32..]   tile table: int4 {expert, base, valid, 0}
#define MAX_TILES 136   // 256-row tiles: <= 128 + 7
#define NCHUNK 1024     // router blocks; 16 tokens per chunk

__device__ __forceinline__ void gload16(const void* g, void* l) {
  __builtin_amdgcn_global_load_lds(
      (const __attribute__((address_space(1))) void*)g,
      (__attribute__((address_space(3))) void*)l, 16, 0, 0);
}

__device__ __forceinline__ float bf2f(unsigned short u) {
  union { unsigned int i; float f; } v; v.i = ((unsigned int)u) << 16; return v.f;
}
__device__ __forceinline__ unsigned short f2bf(float f) {
  __hip_bfloat16 h = __float2bfloat16(f);
  return __builtin_bit_cast(unsigned short, h);
}

// compiler memory fence + hw barrier (no sched_barrier: m141)
#define CBAR() do { asm volatile("" ::: "memory"); __builtin_amdgcn_s_barrier(); asm volatile("" ::: "memory"); } while (0)
#define VMC6() asm volatile("s_waitcnt vmcnt(6)" ::: "memory")
#define VMC0() asm volatile("s_waitcnt vmcnt(0)" ::: "memory")

// src fp32 [B][R][C] -> dst bf16 [B][C][R]
__global__ void transpose_cvt(const float* __restrict__ src,
                              unsigned short* __restrict__ dst, int R, int C) {
  __shared__ float tile[32][33];
  int b = blockIdx.z;
  int c0 = blockIdx.x * 32, r0 = blockIdx.y * 32;
  src += (size_t)b * R * C;
  dst += (size_t)b * R * C;
  int tx = threadIdx.x, ty = threadIdx.y;  // 32 x 8
#pragma unroll
  for (int i = 0; i < 32; i += 8)
    tile[ty + i][tx] = src[(size_t)(r0 + ty + i) * C + c0 + tx];
  __syncthreads();
#pragma unroll
  for (int i = 0; i < 32; i += 8)
    dst[(size_t)(c0 + ty + i) * R + r0 + tx] = f2bf(tile[tx][ty + i]);
}

// ---------------- router: fp32 logits, softmax, top-2, fused x->bf16 ----------------
__global__ __launch_bounds__(256) void router_kernel(
    const float* __restrict__ x, const float* __restrict__ Wr,
    const float* __restrict__ br, unsigned short* __restrict__ xbf,
    float* __restrict__ scores, int* __restrict__ idx,
    int* __restrict__ blk_hist) {
  __shared__ int cnt[8];
  int tid = threadIdx.x, lane = tid & 63, w = tid >> 6;
  if (tid < 8) cnt[tid] = 0;
  __syncthreads();
  int t0 = blockIdx.x * 16 + w * 4;
  const float* xr = x + (size_t)t0 * 2048;
  unsigned short* xo = xbf + (size_t)t0 * 2048;
  float acc[4][8] = {};
#pragma unroll
  for (int j = 0; j < 8; ++j) {
    int h0 = j * 256 + lane * 4;
    float4 xv[4];
#pragma unroll
    for (int t = 0; t < 4; ++t) xv[t] = *(const float4*)(xr + (size_t)t * 2048 + h0);
#pragma unroll
    for (int t = 0; t < 4; ++t) {
      ushort4 p;
      p.x = f2bf(xv[t].x); p.y = f2bf(xv[t].y);
      p.z = f2bf(xv[t].z); p.w = f2bf(xv[t].w);
      *(ushort4*)(xo + (size_t)t * 2048 + h0) = p;
    }
    const float4* wp = (const float4*)(Wr + (size_t)h0 * 8);
#pragma unroll
    for (int c = 0; c < 4; ++c) {
      float4 w0 = wp[2 * c], w1 = wp[2 * c + 1];
      float xc0 = (c == 0) ? xv[0].x : (c == 1) ? xv[0].y : (c == 2) ? xv[0].z : xv[0].w;
      float xc1 = (c == 0) ? xv[1].x : (c == 1) ? xv[1].y : (c == 2) ? xv[1].z : xv[1].w;
      float xc2 = (c == 0) ? xv[2].x : (c == 1) ? xv[2].y : (c == 2) ? xv[2].z : xv[2].w;
      float xc3 = (c == 0) ? xv[3].x : (c == 1) ? xv[3].y : (c == 2) ? xv[3].z : xv[3].w;
      acc[0][0] += xc0 * w0.x; acc[0][1] += xc0 * w0.y; acc[0][2] += xc0 * w0.z; acc[0][3] += xc0 * w0.w;
      acc[0][4] += xc0 * w1.x; acc[0][5] += xc0 * w1.y; acc[0][6] += xc0 * w1.z; acc[0][7] += xc0 * w1.w;
      acc[1][0] += xc1 * w0.x; acc[1][1] += xc1 * w0.y; acc[1][2] += xc1 * w0.z; acc[1][3] += xc1 * w0.w;
      acc[1][4] += xc1 * w1.x; acc[1][5] += xc1 * w1.y; acc[1][6] += xc1 * w1.z; acc[1][7] += xc1 * w1.w;
      acc[2][0] += xc2 * w0.x; acc[2][1] += xc2 * w0.y; acc[2][2] += xc2 * w0.z; acc[2][3] += xc2 * w0.w;
      acc[2][4] += xc2 * w1.x; acc[2][5] += xc2 * w1.y; acc[2][6] += xc2 * w1.z; acc[2][7] += xc2 * w1.w;
      acc[3][0] += xc3 * w0.x; acc[3][1] += xc3 * w0.y; acc[3][2] += xc3 * w0.z; acc[3][3] += xc3 * w0.w;
      acc[3][4] += xc3 * w1.x; acc[3][5] += xc3 * w1.y; acc[3][6] += xc3 * w1.z; acc[3][7] += xc3 * w1.w;
    }
  }
#pragma unroll
  for (int t = 0; t < 4; ++t)
#pragma unroll
    for (int e = 0; e < 8; ++e)
#pragma unroll
      for (int off = 32; off > 0; off >>= 1)
        acc[t][e] += __shfl_xor(acc[t][e], off);
  if (lane < 4) {
    int t = t0 + lane;
    float l[8];
#pragma unroll
    for (int e = 0; e < 8; ++e) {
      float v = (lane == 0) ? acc[0][e] : (lane == 1) ? acc[1][e]
              : (lane == 2) ? acc[2][e] : acc[3][e];
      l[e] = v + br[e];
    }
    float mx = l[0];
#pragma unroll
    for (int e = 1; e < 8; ++e) mx = fmaxf(mx, l[e]);
    float se = 0.f;
#pragma unroll
    for (int e = 0; e < 8; ++e) se += __expf(l[e] - mx);
    float inv = 1.f / se;
    int e1 = 0; float b1 = l[0];
#pragma unroll
    for (int e = 1; e < 8; ++e) if (l[e] > b1) { b1 = l[e]; e1 = e; }
    int e2 = -1; float b2 = -1e30f;
#pragma unroll
    for (int e = 0; e < 8; ++e) if (e != e1 && l[e] > b2) { b2 = l[e]; e2 = e; }
    idx[2 * t] = e1; idx[2 * t + 1] = e2;
    scores[2 * t] = __expf(b1 - mx) * inv;
    scores[2 * t + 1] = __expf(b2 - mx) * inv;
    atomicAdd(&cnt[e1], 1);   // LDS atomics only
    atomicAdd(&cnt[e2], 1);
  }
  __syncthreads();
  if (tid < 8) blk_hist[blockIdx.x * 8 + tid] = cnt[tid];
}

// ---------------- scan: parallel prefix over chunk histograms (256-row tiles) ----------------
__global__ __launch_bounds__(512) void scan_kernel(
    const int* __restrict__ blk_hist, int* __restrict__ chunk_base,
    int* __restrict__ meta, int* __restrict__ rowlist) {
  __shared__ int stot[8], soff[8];
  int tid = threadIdx.x, lane = tid & 63, e = tid >> 6;
  int running = 0;
  for (int g = 0; g < NCHUNK / 64; ++g) {
    int c = g * 64 + lane;
    int v = blk_hist[c * 8 + e];
    int orig = v;
#pragma unroll
    for (int off = 1; off < 64; off <<= 1) {
      int n = __shfl_up(v, off);
      if (lane >= off) v += n;
    }
    chunk_base[c * 8 + e] = running + v - orig;
    running += __shfl(v, 63);
  }
  if (lane == 0) stot[e] = running;
  __syncthreads();
  if (tid == 0) {
    int off = 0, nt = 0;
    int4* tbl = (int4*)(meta + M_TBL);
    for (int ee = 0; ee < 8; ++ee) {
      int c = stot[ee];
      meta[M_OFF + ee] = off; soff[ee] = off;
      int tiles = (c + 255) >> 8;
      for (int t = 0; t < tiles; ++t)
        tbl[nt++] = make_int4(ee, off + t * 256, min(256, c - t * 256), 0);
      off += tiles << 8;
    }
    meta[M_NT] = nt;
  }
  __syncthreads();
  for (int ee = 0; ee < 8; ++ee) {
    int c = stot[ee], end = ((c + 255) >> 8) << 8;
    for (int i = c + tid; i < end; i += 512) rowlist[soff[ee] + i] = 0;
  }
}

// ---------------- scatter: ballot-ranked, zero atomics ----------------
__global__ void scatter_kernel(const int* __restrict__ idx,
                               const int* __restrict__ chunk_base,
                               const int* __restrict__ meta,
                               int* __restrict__ rowlist) {
  int c = blockIdx.x, lane = threadIdx.x;
  int entry = c * 32 + lane;
  int e = (lane < 32) ? idx[entry] : -1;
#pragma unroll
  for (int ee = 0; ee < 8; ++ee) {
    unsigned long long m = __ballot(e == ee);
    if (e == ee) {
      int rank = __popcll(m & ((1ull << lane) - 1));
      rowlist[meta[M_OFF + ee] + chunk_base[c * 8 + ee] + rank] = entry;
    }
  }
}

// ============ 256x256 8-phase GEMM, 2 K-tiles per iter (m201-exact) ============
// 512 thr = 8 waves (2M x 4N); BK=64. LDS 128KiB: B at 0 (buf0/buf1 @ 0/32768),
// A at 65536 (+0/32768). Each buf: half0 16KB, half1 16KB.
// ALL LDS offsets compile-time (2-tile unroll); per-lane base ptrs hoisted.
// Stage schedule per iter (1 half-slot = 2 gload16 per phase):
//   ph0:A1(o) ph1:B0(e+2) ph2:B1(e+2) ph3:A0(e+2) ph4:A1(e+2) ph5:B0(o+2) ph6:B1(o+2) ph7:A0(o+2)
// vmcnt(6) only at end of ph3 and ph7 (retires through next tile's last slot).
// Swizzle: read byte ^= swz; stage source inverse-swizzled, LDS dest linear.

#define STG(P0, P1, KOFF, D) { gload16((P0) + (KOFF), (D)); gload16((P1) + (KOFF), (D) + 8192); }

#define RD_A(OFF) do { _Pragma("unroll") for (int m = 0; m < 4; ++m) { \
  av[m][0] = *(const bf16x8*)(aP0 + (OFF) + m * 2048); \
  av[m][1] = *(const bf16x8*)(aP1 + (OFF) + m * 2048); } } while (0)

#define RD_B(BV, OFF) do { _Pragma("unroll") for (int n = 0; n < 2; ++n) { \
  BV[n][0] = *(const bf16x8*)(bP0 + (OFF) + n * 2048); \
  BV[n][1] = *(const bf16x8*)(bP1 + (OFF) + n * 2048); } } while (0)

#define CLUSTER(MO, NO, BV) do { \
  __builtin_amdgcn_s_setprio(1); \
  _Pragma("unroll") for (int kk = 0; kk < 2; ++kk) \
  _Pragma("unroll") for (int m = 0; m < 4; ++m) \
  _Pragma("unroll") for (int n = 0; n < 2; ++n) \
    acc[(MO) + m][(NO) + n] = __builtin_amdgcn_mfma_f32_16x16x32_bf16( \
        av[m][kk], BV[n][kk], acc[(MO) + m][(NO) + n], 0, 0, 0); \
  __builtin_amdgcn_s_setprio(0); \
} while (0)

// one full 2-K-tile iteration body (phases 0..7)
#define GEMM_ITER(PF) \
    /* ---- tile e (buf 0) ---- */ \
    RD_A(0); RD_B(bv0, 0); \
    STG(paG[1][0], paG[1][1], 128, dA + 32768 + 16384);            /* A1(o) */ \
    CBAR(); CLUSTER(0, 0, bv0); CBAR(); \
    RD_B(bv1, 4096); \
    if (PF) STG(pbG[0][0], pbG[0][1], 256, dB);                    /* B0(e+2) */ \
    CBAR(); CLUSTER(0, 2, bv1); CBAR(); \
    RD_A(8192); \
    if (PF) STG(pbG[1][0], pbG[1][1], 256, dB + 16384);            /* B1(e+2) */ \
    CBAR(); CLUSTER(4, 0, bv0); CBAR(); \
    if (PF) STG(paG[0][0], paG[0][1], 256, dA);                    /* A0(e+2) */ \
    CBAR(); CLUSTER(4, 2, bv1); \
    if (PF) { VMC6(); } else { VMC0(); } \
    CBAR(); \
    /* ---- tile o (buf 32768) ---- */ \
    RD_A(32768); RD_B(bv0, 32768); \
    if (PF) STG(paG[1][0], paG[1][1], 256, dA + 16384);            /* A1(e+2) */ \
    CBAR(); CLUSTER(0, 0, bv0); CBAR(); \
    RD_B(bv1, 32768 + 4096); \
    if (PF) STG(pbG[0][0], pbG[0][1], 384, dB + 32768);            /* B0(o+2) */ \
    CBAR(); CLUSTER(0, 2, bv1); CBAR(); \
    RD_A(32768 + 8192); \
    if (PF) STG(pbG[1][0], pbG[1][1], 384, dB + 32768 + 16384);    /* B1(o+2) */ \
    CBAR(); CLUSTER(4, 0, bv0); CBAR(); \
    if (PF) STG(paG[0][0], paG[0][1], 384, dA + 32768);            /* A0(o+2) */ \
    CBAR(); CLUSTER(4, 2, bv1); \
    if (PF) { VMC6(); } else { VMC0(); } \
    CBAR(); \
    _Pragma("unroll") for (int h_ = 0; h_ < 2; ++h_) \
    _Pragma("unroll") for (int j_ = 0; j_ < 2; ++j_) { paG[h_][j_] += 256; pbG[h_][j_] += 256; }

#define GEMM_PROLOGUE() \
    STG(pbG[0][0], pbG[0][1], 0, dB); \
    STG(pbG[1][0], pbG[1][1], 0, dB + 16384); \
    STG(paG[0][0], paG[0][1], 0, dA); \
    STG(paG[1][0], paG[1][1], 0, dA + 16384); \
    STG(pbG[0][0], pbG[0][1], 128, dB + 32768); \
    STG(pbG[1][0], pbG[1][1], 128, dB + 32768 + 16384); \
    STG(paG[0][0], paG[0][1], 128, dA + 32768); \
    VMC6(); CBAR();

// ---------------- expert GEMM: z[entry] = (x[t] @ We[e] + be[e]) * score ----------------
__global__ __launch_bounds__(512, 2) void expert_gemm(
    const unsigned short* __restrict__ xbf,   // [16384][2048] bf16
    const unsigned short* __restrict__ WeT,   // [8][1024][2048] bf16 (n-major)
    const float* __restrict__ be,             // [8][1024]
    const float* __restrict__ scores,         // [32768]
    const int* __restrict__ rowlist,
    const int* __restrict__ meta,
    unsigned short* __restrict__ z) {         // [32768][1024] bf16
  __shared__ char smem[131072];
  __shared__ int lrows[256];
  int nt = meta[M_NT];
  int flat = blockIdx.y * 4 + blockIdx.x;       // 544 blocks
  int work = (flat & 7) * 68 + (flat >> 3);     // XCD-contiguous chunks of 68
  int tileid = work >> 2, nb = work & 3;
  if (tileid >= nt) return;
  int4 tt = ((const int4*)(meta + M_TBL))[tileid];
  int e = tt.x, base = tt.y, valid = tt.z;
  int n0 = nb * 256;
  int tid = threadIdx.x, lane = tid & 63, w = tid >> 6;
  if (tid < 256) lrows[tid] = rowlist[base + tid];
  __syncthreads();
  int wm = w >> 2, wn = w & 3;
  int fl = lane & 15, q = lane >> 4;
  // staging geometry
  int rowb = tid >> 3;                       // 0..63
  int dstB = rowb * 128 + (tid & 7) * 16;    // linear LDS dest
  int s16 = ((tid & 7) ^ (rowb & 7)) * 16;   // inverse-swizzled source slot
  const char* paG[2][2]; const char* pbG[2][2];
#pragma unroll
  for (int h = 0; h < 2; ++h)
#pragma unroll
    for (int j = 0; j < 2; ++j) {
      int R = h * 128 + j * 64 + rowb;
      paG[h][j] = (const char*)xbf + (size_t)(lrows[R] >> 1) * 4096 + s16;
      pbG[h][j] = (const char*)WeT + ((size_t)e * 1024 + n0 + R) * 4096 + s16;
    }
  char* dA = smem + 65536 + dstB;
  char* dB = smem + dstB;
  // hoisted per-lane read base pointers (loop body uses only imm offsets)
  int sw16 = (fl & 7) << 4;
  int axk0 = (q * 16) ^ sw16, axk1 = (64 + q * 16) ^ sw16;
  const char* aP0 = smem + 65536 + (wm * 128 + fl) * 128 + axk0;
  const char* aP1 = smem + 65536 + (wm * 128 + fl) * 128 + axk1;
  const char* bP0 = smem + (wn * 64 + fl) * 128 + axk0;
  const char* bP1 = smem + (wn * 64 + fl) * 128 + axk1;
  GEMM_PROLOGUE();
  f32x4 acc[8][4] = {};
  bf16x8 av[4][2], bv0[2][2], bv1[2][2];
  const int NT = 32;  // K=2048/64 (even)
  for (int t2 = 0; t2 < NT; t2 += 2) {
    const bool pf = (t2 + 2) < NT;
    GEMM_ITER(pf);
  }
  // epilogue
  float bev[4];
#pragma unroll
  for (int nc = 0; nc < 4; ++nc)
    bev[nc] = be[e * 1024 + n0 + wn * 64 + (nc >> 1) * 32 + (nc & 1) * 16 + fl];
#pragma unroll
  for (int mi = 0; mi < 8; ++mi) {
    int rowbase = wm * 128 + (mi >> 2) * 64 + (mi & 3) * 16 + q * 4;
#pragma unroll
    for (int r = 0; r < 4; ++r) {
      int row = rowbase + r;
      if (row < valid) {
        int entry = lrows[row];
        float s = scores[entry];
        unsigned short* zr = z + (size_t)entry * 1024 + n0 + wn * 64 + fl;
#pragma unroll
        for (int nc = 0; nc < 4; ++nc)
          zr[(nc >> 1) * 32 + (nc & 1) * 16] = f2bf((acc[mi][nc][r] + bev[nc]) * s);
      }
    }
  }
}

// ---------------- combine GEMM: out = y @ Wc + bc (fp32 out) ----------------
__global__ __launch_bounds__(512, 2) void combine_gemm(
    const unsigned short* __restrict__ y,    // [16384][1024] bf16
    const unsigned short* __restrict__ WcT,  // [2048][1024] bf16 (n-major)
    const float* __restrict__ bc,            // [2048]
    float* __restrict__ out) {               // [16384][2048] fp32
  __shared__ char smem[131072];
  int flat = blockIdx.y * 8 + blockIdx.x;     // 512 blocks
  int work = (flat & 7) * 64 + (flat >> 3);
  int mtile = work >> 3, nb = work & 7;
  int m0 = mtile * 256, n0 = nb * 256;
  int tid = threadIdx.x, lane = tid & 63, w = tid >> 6;
  int wm = w >> 2, wn = w & 3;
  int fl = lane & 15, q = lane >> 4;
  int rowb = tid >> 3;
  int dstB = rowb * 128 + (tid & 7) * 16;
  int s16 = ((tid & 7) ^ (rowb & 7)) * 16;
  const char* paG[2][2]; const char* pbG[2][2];
#pragma unroll
  for (int h = 0; h < 2; ++h)
#pragma unroll
    for (int j = 0; j < 2; ++j) {
      int R = h * 128 + j * 64 + rowb;
      paG[h][j] = (const char*)y + (size_t)(m0 + R) * 2048 + s16;
      pbG[h][j] = (const char*)WcT + (size_t)(n0 + R) * 2048 + s16;
    }
  char* dA = smem + 65536 + dstB;
  char* dB = smem + dstB;
  int sw16 = (fl & 7) << 4;
  int axk0 = (q * 16) ^ sw16, axk1 = (64 + q * 16) ^ sw16;
  const char* aP0 = smem + 65536 + (wm * 128 + fl) * 128 + axk0;
  const char* aP1 = smem + 65536 + (wm * 128 + fl) * 128 + axk1;
  const char* bP0 = smem + (wn * 64 + fl) * 128 + axk0;
  const char* bP1 = smem + (wn * 64 + fl) * 128 + axk1;
  GEMM_PROLOGUE();
  f32x4 acc[8][4] = {};
  bf16x8 av[4][2], bv0[2][2], bv1[2][2];
  const int NT = 16;  // K=1024/64 (even)
  for (int t2 = 0; t2 < NT; t2 += 2) {
    const bool pf = (t2 + 2) < NT;
    GEMM_ITER(pf);
  }
  float bcv[4];
#pragma unroll
  for (int nc = 0; nc < 4; ++nc)
    bcv[nc] = bc[n0 + wn * 64 + (nc >> 1) * 32 + (nc & 1) * 16 + fl];
#pragma unroll
  for (int mi = 0; mi < 8; ++mi) {
    int rowbase = m0 + wm * 128 + (mi >> 2) * 64 + (mi & 3) * 16 + q * 4;
#pragma unroll
    for (int r = 0; r < 4; ++r) {
      float* orow = out + (size_t)(rowbase + r) * 2048 + n0 + wn * 64 + fl;
#pragma unroll
      for (int nc = 0; nc < 4; ++nc)
        orow[(nc >> 1) * 32 + (nc & 1) * 16] = acc[mi][nc][r] + bcv[nc];
    }
  }
}

// ---------------- weighted sum: y[t] = z[2t] + z[2t+1] (both pre-weighted) ----------------
__global__ void wsum_kernel(const unsigned short* __restrict__ z,
                            unsigned short* __restrict__ y) {
  size_t i = ((size_t)blockIdx.x * 256 + threadIdx.x) * 8;
  size_t t = i >> 10, d = i & 1023;
  int4 za = *(const int4*)(z + (t * 2) * 1024 + d);
  int4 zb = *(const int4*)(z + (t * 2 + 1) * 1024 + d);
  int4 r;
  const unsigned short* pa = (const unsigned short*)&za;
  const unsigned short* pb = (const unsigned short*)&zb;
  unsigned short* pr = (unsigned short*)&r;
#pragma unroll
  for (int j = 0; j < 8; ++j) pr[j] = f2bf(bf2f(pa[j]) + bf2f(pb[j]));
  *(int4*)(y + i) = r;
}

// ---------------- launch ----------------
extern "C" void kernel_launch(void* const* d_in, const int* in_sizes, int n_in,
                              void* d_out, int out_size, void* d_ws, size_t ws_size,
                              hipStream_t stream) {
  const float* x  = (const float*)d_in[0];
  const float* Wr = (const float*)d_in[1];
  const float* br = (const float*)d_in[2];
  const float* We = (const float*)d_in[3];
  const float* be = (const float*)d_in[4];
  const float* Wc = (const float*)d_in[5];
  const float* bc = (const float*)d_in[6];
  float* out = (float*)d_out;

  char* ws = (char*)d_ws;
  size_t o = 0;
  auto alloc = [&](size_t b) {
    char* p = ws + o;
    o = (o + b + 255) & ~(size_t)255;
    return p;
  };
  unsigned short* xbf = (unsigned short*)alloc(16384UL * 2048 * 2);
  unsigned short* WeT = (unsigned short*)alloc(8UL * 1024 * 2048 * 2);
  unsigned short* WcT = (unsigned short*)alloc(2048UL * 1024 * 2);
  unsigned short* z   = (unsigned short*)alloc(32768UL * 1024 * 2);
  unsigned short* yw  = (unsigned short*)alloc(16384UL * 1024 * 2);
  float* scores = (float*)alloc(32768UL * 4);
  int* idx      = (int*)alloc(32768UL * 4);
  int* rowlist  = (int*)alloc(36864UL * 4);
  int* meta     = (int*)alloc(8192);
  int* blk_hist = (int*)alloc(NCHUNK * 8 * 4);
  int* chunk_base = (int*)alloc(NCHUNK * 8 * 4);
  (void)ws_size; (void)in_sizes; (void)n_in; (void)out_size;

  hipLaunchKernelGGL(transpose_cvt, dim3(32, 64, 8), dim3(32, 8), 0, stream, We, WeT, 2048, 1024);
  hipLaunchKernelGGL(transpose_cvt, dim3(64, 32, 1), dim3(32, 8), 0, stream, Wc, WcT, 1024, 2048);
  hipLaunchKernelGGL(router_kernel, dim3(NCHUNK), dim3(256), 0, stream, x, Wr, br, xbf, scores, idx, blk_hist);
  hipLaunchKernelGGL(scan_kernel, dim3(1), dim3(512), 0, stream, blk_hist, chunk_base, meta, rowlist);
  hipLaunchKernelGGL(scatter_kernel, dim3(NCHUNK), dim3(64), 0, stream, idx, chunk_base, meta, rowlist);
  hipLaunchKernelGGL(expert_gemm, dim3(4, MAX_TILES), dim3(512), 0, stream,
                     xbf, WeT, be, scores, rowlist, meta, z);
  hipLaunchKernelGGL(wsum_kernel, dim3(8192), dim3(256), 0, stream, z, yw);
  hipLaunchKernelGGL(combine_gemm, dim3(8, 64), dim3(512), 0, stream, yw, WcT, bc, out);
}